// Round 12
// baseline (140.269 us; speedup 1.0000x reference)
//
#include <hip/hip_runtime.h>

#define SLEN 4096
#define NB 4
#define DIN 256
#define DOUT 64
#define KVSPLIT 8
#define KVBLK 64
#define QBLK 256                         // q-rows per block (8 waves x 32)
#define CHUNK (SLEN / KVSPLIT)           // 512
#define NT (CHUNK / KVBLK)               // 8 kv tiles per block

typedef _Float16 f16;
typedef _Float16 f16x8 __attribute__((ext_vector_type(8)));
typedef _Float16 f16x4 __attribute__((ext_vector_type(4)));
typedef _Float16 f16x2 __attribute__((ext_vector_type(2)));
typedef float f32x4 __attribute__((ext_vector_type(4)));

#define QSCALE 0.1803368801111204f   // 0.125 * log2(e)
#define PSHIFT2 4.328085122666891f   // 3 * log2(e); uniform shift, cancels in O/L

// cvt_pkrtz returns __fp16x2; bit_cast to our _Float16x2
static __device__ __forceinline__ f16x2 pkrtz(float a, float b) {
  return __builtin_bit_cast(f16x2, __builtin_amdgcn_cvt_pkrtz(a, b));
}

// async global->LDS, 16B/lane; LDS dest is wave-uniform base + lane*16
#define GLD16(gsrc, ldst)                                          \
  __builtin_amdgcn_global_load_lds(                                \
      (const __attribute__((address_space(1))) void*)(gsrc),       \
      (__attribute__((address_space(3))) void*)(ldst), 16, 0, 0)

// ---------------------------------------------------------------------------
// Setup: W transpose (w [3][256][64] f32 -> wth [3][64][256] f16) + zero the
// atomic-merge buffers (out, pL).
// ---------------------------------------------------------------------------
__global__ __launch_bounds__(256) void setup_kernel(
    const float* __restrict__ w, f16* __restrict__ wth,
    float* __restrict__ out, float* __restrict__ pL) {
  int gtid = blockIdx.x * 256 + threadIdx.x;       // 0 .. 65535
  if (gtid < 3 * DIN * DOUT) {
    int m = gtid / (DIN * DOUT);
    int r = gtid - m * (DIN * DOUT);
    int k = r >> 6, o = r & 63;
    wth[(m * DOUT + o) * DIN + k] = (f16)w[gtid];
  }
  const int ntot = NB * SLEN * DOUT;               // 1,048,576
  for (int i = gtid; i < ntot + NB * SLEN; i += 65536) {
    if (i < ntot) out[i] = 0.f;
    else pL[i - ntot] = 0.f;
  }
}

// ---------------------------------------------------------------------------
// Projection, grid (1024, 3): one wave per block, one m per block.
// ---------------------------------------------------------------------------
__global__ __launch_bounds__(64) void proj_kernel(
    const float* __restrict__ x, const f16* __restrict__ wth,
    f16* __restrict__ qh, f16* __restrict__ kh, f16* __restrict__ vth) {
  __shared__ alignas(16) f16 tbuf[64 * 24];
  const int lane = threadIdx.x;
  const int c = lane & 15, g = lane >> 4;
  const int m = blockIdx.y;
  const int tb = blockIdx.x * 16;
  const int b = tb >> 12, s0 = tb & 4095;

  f16x8 a[8];
  {
    const float* xr = x + (size_t)(tb + c) * DIN + g * 8;
#pragma unroll
    for (int ks = 0; ks < 8; ++ks) {
      f32x4 lo = *(const f32x4*)(xr + ks * 32);
      f32x4 hi = *(const f32x4*)(xr + ks * 32 + 4);
      f16x8 av;
#pragma unroll
      for (int j = 0; j < 4; ++j) { av[j] = (f16)lo[j]; av[j + 4] = (f16)hi[j]; }
      a[ks] = av;
    }
  }

  const f16* wb = wth + (size_t)m * DOUT * DIN + (size_t)c * DIN + g * 8;
  f32x4 acc[4];
#pragma unroll
  for (int nt = 0; nt < 4; ++nt) acc[nt] = (f32x4){0.f, 0.f, 0.f, 0.f};
#pragma unroll
  for (int ks = 0; ks < 8; ++ks)
#pragma unroll
    for (int nt = 0; nt < 4; ++nt) {
      f16x8 bf = *(const f16x8*)(wb + (size_t)(nt * 16) * DIN + ks * 32);
      acc[nt] = __builtin_amdgcn_mfma_f32_16x16x32_f16(a[ks], bf, acc[nt], 0, 0, 0);
    }

  if (m < 2) {
#pragma unroll
    for (int nt = 0; nt < 4; ++nt)
#pragma unroll
      for (int rr = 0; rr < 4; ++rr)
        tbuf[(4 * g + rr) * 72 + nt * 16 + c] =
            (f16)(m == 0 ? acc[nt][rr] * QSCALE : acc[nt][rr]);
    const int rw = lane >> 2, cb = (lane & 3) * 16;
    f16x8 r0 = *(const f16x8*)&tbuf[rw * 72 + cb];
    f16x8 r1 = *(const f16x8*)&tbuf[rw * 72 + cb + 8];
    f16* dst = (m == 0 ? qh : kh) + (size_t)(tb + rw) * DOUT + cb;
    *(f16x8*)(dst) = r0;
    *(f16x8*)(dst + 8) = r1;
  } else {
#pragma unroll
    for (int nt = 0; nt < 4; ++nt)
#pragma unroll
      for (int rr = 0; rr < 4; ++rr)
        tbuf[(nt * 16 + c) * 24 + 4 * g + rr] = (f16)acc[nt][rr];
    f16x8 r0 = *(const f16x8*)&tbuf[lane * 24];
    f16x8 r1 = *(const f16x8*)&tbuf[lane * 24 + 8];
    f16* dst = vth + ((size_t)b * DOUT + lane) * SLEN + s0;
    *(f16x8*)(dst) = r0;
    *(f16x8*)(dst + 8) = r1;
  }
}

// ---------------------------------------------------------------------------
// Flash attention v3: 512 blocks (4 b x 8 split x 16 q-blocks), 8 WAVES,
// each wave owns 32 q-rows -> 16 waves/CU (2 blocks x 8; 2x R9's 8).
// K/V staged once per block, shared by 8 waves.  PSHIFT2 folded into MFMA
// C-init; P packed with cvt_pkrtz.  Atomic merge into out/pL; norm divides.
// LDS 64 KB -> 2 blocks/CU.
// ---------------------------------------------------------------------------
__global__ __launch_bounds__(512, 4) void attn_kernel(
    const f16* __restrict__ qh, const f16* __restrict__ kh,
    const f16* __restrict__ vth, float* __restrict__ out,
    float* __restrict__ pL) {
  __shared__ alignas(16) f16 kb[2][KVBLK * 64];   // 16 KB
  __shared__ alignas(16) f16 vb[2][KVBLK * 64];   // 16 KB
  __shared__ alignas(16) f16 pbuf[8][32 * 64];    // 32 KB (per-wave 2 halves)

  const int tid = threadIdx.x;
  const int lane = tid & 63;
  const int c = lane & 15, g = lane >> 4;
  const int wv = tid >> 6;

  // bijective XCD-contiguous swizzle (nwg=512 = 8 x 64)
  const int wg = ((blockIdx.x & 7) << 6) + (blockIdx.x >> 3);
  const int b = wg >> 7;
  const int w128 = wg & 127;
  const int split = w128 >> 4;                    // 0..7
  const int qb = w128 & 15;                       // 0..15
  const int q0 = qb * QBLK + wv * 32;             // this wave's 32 rows
  const int kv0 = split * CHUNK;

  f16* plds = pbuf[wv];

  // staging map: 512 threads x 16B cover one 64x64 f16 tile
  const int srow = tid >> 3;                      // 0..63
  const int scol = (tid & 7) * 8;
  const f16* kgbase = kh + (size_t)b * SLEN * DOUT;
  const f16* vgbase = vth + (size_t)b * DOUT * SLEN;

  // Q frags for both 16-row halves (pre-scaled by 0.125*log2e)
  f16x8 qf[4];
#pragma unroll
  for (int h = 0; h < 2; ++h) {
    const f16* qr = qh + ((size_t)(b * SLEN + q0 + 16 * h + c)) * DOUT + g * 8;
    qf[2 * h] = *(const f16x8*)(qr);
    qf[2 * h + 1] = *(const f16x8*)(qr + 32);
  }

  f32x4 o0[4], o1[4];
#pragma unroll
  for (int nt = 0; nt < 4; ++nt) {
    o0[nt] = (f32x4){0.f, 0.f, 0.f, 0.f};
    o1[nt] = (f32x4){0.f, 0.f, 0.f, 0.f};
  }
  float lr0 = 0.f, lr1 = 0.f;
  const f32x4 zinit = (f32x4){-PSHIFT2, -PSHIFT2, -PSHIFT2, -PSHIFT2};

  auto stage = [&](int sel, int kv) {
    int sw = scol ^ ((srow & 7) << 3);            // source-side swizzle
    GLD16(kgbase + (size_t)(kv + srow) * DOUT + sw,
          (char*)(&kb[sel][0]) + wv * 1024);
    GLD16(vgbase + (size_t)srow * SLEN + kv + sw,
          (char*)(&vb[sel][0]) + wv * 1024);
  };

  stage(0, kv0);
  __syncthreads();

#pragma unroll 2
  for (int t = 0; t < NT; ++t) {
    const int sel = t & 1;
    if (t + 1 < NT) stage(sel ^ 1, kv0 + (t + 1) * KVBLK);

    // ---- S^T = K x Q^T for both halves; K frags read ONCE; C-init=-PSHIFT2
    f32x4 s0[4], s1[4];
    __builtin_amdgcn_s_setprio(1);
#pragma unroll
    for (int t4 = 0; t4 < 4; ++t4) {
      f16x8 k0 = *(const f16x8*)&kb[sel][(16 * t4 + c) * 64 + 8 * (g ^ (c & 7))];
      f16x8 k1 = *(const f16x8*)&kb[sel][(16 * t4 + c) * 64 + 8 * ((g + 4) ^ (c & 7))];
      s0[t4] = __builtin_amdgcn_mfma_f32_16x16x32_f16(k0, qf[0], zinit, 0, 0, 0);
      s0[t4] = __builtin_amdgcn_mfma_f32_16x16x32_f16(k1, qf[1], s0[t4], 0, 0, 0);
      s1[t4] = __builtin_amdgcn_mfma_f32_16x16x32_f16(k0, qf[2], zinit, 0, 0, 0);
      s1[t4] = __builtin_amdgcn_mfma_f32_16x16x32_f16(k1, qf[3], s1[t4], 0, 0, 0);
    }
    __builtin_amdgcn_s_setprio(0);

    // ---- lane-local exp2; pack via cvt_pkrtz ----
    f16x4 pk0[4], pk1[4];
#pragma unroll
    for (int t4 = 0; t4 < 4; ++t4) {
      float e00 = exp2f(s0[t4][0]), e01 = exp2f(s0[t4][1]);
      float e02 = exp2f(s0[t4][2]), e03 = exp2f(s0[t4][3]);
      float e10 = exp2f(s1[t4][0]), e11 = exp2f(s1[t4][1]);
      float e12 = exp2f(s1[t4][2]), e13 = exp2f(s1[t4][3]);
      lr0 += (e00 + e01) + (e02 + e03);
      lr1 += (e10 + e11) + (e12 + e13);
      f16x2 a0 = pkrtz(e00, e01), a1 = pkrtz(e02, e03);
      f16x2 b0 = pkrtz(e10, e11), b1 = pkrtz(e12, e13);
      pk0[t4] = (f16x4){a0[0], a0[1], a1[0], a1[1]};
      pk1[t4] = (f16x4){b0[0], b0[1], b1[0], b1[1]};
    }

    // ---- P^T -> wave-private LDS (both halves) ----
#pragma unroll
    for (int t4 = 0; t4 < 4; ++t4) {
      int sw = (16 * t4 + 4 * g) ^ ((c & 7) << 3);
      *(f16x4*)&plds[c * 64 + sw] = pk0[t4];
      *(f16x4*)&plds[1024 + c * 64 + sw] = pk1[t4];
    }

    // ---- PV: V frags read ONCE, feed both halves ----
    __builtin_amdgcn_s_setprio(1);
#pragma unroll
    for (int s2 = 0; s2 < 2; ++s2) {
      int sw = (s2 * 32 + g * 8) ^ ((c & 7) << 3);
      f16x8 pa0 = *(const f16x8*)&plds[c * 64 + sw];
      f16x8 pa1 = *(const f16x8*)&plds[1024 + c * 64 + sw];
#pragma unroll
      for (int nt = 0; nt < 4; ++nt) {
        f16x8 vf = *(const f16x8*)&vb[sel][(16 * nt + c) * 64 + 8 * ((g + 4 * s2) ^ (c & 7))];
        o0[nt] = __builtin_amdgcn_mfma_f32_16x16x32_f16(pa0, vf, o0[nt], 0, 0, 0);
        o1[nt] = __builtin_amdgcn_mfma_f32_16x16x32_f16(pa1, vf, o1[nt], 0, 0, 0);
      }
    }
    __builtin_amdgcn_s_setprio(0);

    __syncthreads();  // drains staging vmcnt; guards buffer reuse
  }

  // ---- merge partials (pure sums; PSHIFT2 cancels in final division) ----
  const size_t rowb = (size_t)b * SLEN + q0;
#pragma unroll
  for (int nt = 0; nt < 4; ++nt)
#pragma unroll
    for (int r = 0; r < 4; ++r) {
      atomicAdd(&out[(rowb + 4 * g + r) * DOUT + nt * 16 + c], o0[nt][r]);
      atomicAdd(&out[(rowb + 16 + 4 * g + r) * DOUT + nt * 16 + c], o1[nt][r]);
    }
  lr0 += __shfl_xor(lr0, 16);
  lr0 += __shfl_xor(lr0, 32);
  lr1 += __shfl_xor(lr1, 16);
  lr1 += __shfl_xor(lr1, 32);
  if (lane < 16) {
    atomicAdd(&pL[rowb + lane], lr0);
    atomicAdd(&pL[rowb + 16 + lane], lr1);
  }
}

// ---------------------------------------------------------------------------
// Normalize: out[row][*] /= pL[row]
// ---------------------------------------------------------------------------
__global__ __launch_bounds__(256) void norm_kernel(
    float* __restrict__ out, const float* __restrict__ pL) {
  int i = blockIdx.x * 256 + threadIdx.x;
  int row = i >> 4;
  float rl = 1.0f / pL[row];
  f32x4 o = *(const f32x4*)&out[(size_t)i * 4];
  o *= rl;
  *(f32x4*)&out[(size_t)i * 4] = o;
}

extern "C" void kernel_launch(void* const* d_in, const int* in_sizes, int n_in,
                              void* d_out, int out_size, void* d_ws, size_t ws_size,
                              hipStream_t stream) {
  const float* x = (const float*)d_in[0];   // [4,4096,256] f32
  const float* w = (const float*)d_in[1];   // [3,256,64]   f32
  float* out = (float*)d_out;               // [4,4096,64]  f32

  const size_t NE = (size_t)NB * SLEN * DOUT;  // 1,048,576
  f16* qh = (f16*)d_ws;                        // 2 MB
  f16* kh = qh + NE;                           // 2 MB
  f16* vth = kh + NE;                          // 2 MB [b][d][s]
  f16* wth = vth + NE;                         // 96 KB
  float* pL = (float*)(wth + 3 * DIN * DOUT);  // 64 KB [b*S]

  hipLaunchKernelGGL(setup_kernel, dim3(256), dim3(256), 0, stream,
                     w, wth, out, pL);
  hipLaunchKernelGGL(proj_kernel, dim3(NB * SLEN / 16, 3), dim3(64), 0, stream,
                     x, wth, qh, kh, vth);
  hipLaunchKernelGGL(attn_kernel, dim3(NB * KVSPLIT * (SLEN / QBLK)), dim3(512),
                     0, stream, qh, kh, vth, out, pL);
  hipLaunchKernelGGL(norm_kernel, dim3(NB * SLEN * DOUT / 4 / 256), dim3(256),
                     0, stream, out, pL);
}

// Round 14
// 114.589 us; speedup vs baseline: 1.2241x; 1.2241x over previous
//
#include <hip/hip_runtime.h>

#define SLEN 4096
#define NB 4
#define DIN 256
#define DOUT 64
#define KVSPLIT 4
#define KVBLK 64
#define QBLK 128                         // q-rows per block (8 waves x 16)
#define CHUNK (SLEN / KVSPLIT)           // 1024
#define NT (CHUNK / KVBLK)               // 16 kv tiles per block

typedef _Float16 f16;
typedef _Float16 f16x8 __attribute__((ext_vector_type(8)));
typedef _Float16 f16x4 __attribute__((ext_vector_type(4)));
typedef _Float16 f16x2 __attribute__((ext_vector_type(2)));
typedef float f32x4 __attribute__((ext_vector_type(4)));

#define QSCALE 0.1803368801111204f   // 0.125 * log2(e)
#define PSHIFT2 4.328085122666891f   // 3 * log2(e); uniform shift, cancels in O/L

// cvt_pkrtz returns __fp16x2; bit_cast to our _Float16x2
static __device__ __forceinline__ f16x2 pkrtz(float a, float b) {
  return __builtin_bit_cast(f16x2, __builtin_amdgcn_cvt_pkrtz(a, b));
}

// async global->LDS, 16B/lane; LDS dest is wave-uniform base + lane*16
#define GLD16(gsrc, ldst)                                          \
  __builtin_amdgcn_global_load_lds(                                \
      (const __attribute__((address_space(1))) void*)(gsrc),       \
      (__attribute__((address_space(3))) void*)(ldst), 16, 0, 0)

// ---------------------------------------------------------------------------
// Setup: W transpose only (w [3][256][64] f32 -> wth [3][64][256] f16).
// No zeroing needed: pO/pL are fully overwritten before being read.
// ---------------------------------------------------------------------------
__global__ __launch_bounds__(256) void setup_kernel(
    const float* __restrict__ w, f16* __restrict__ wth) {
  int gtid = blockIdx.x * 256 + threadIdx.x;       // 0 .. 49151
  if (gtid < 3 * DIN * DOUT) {
    int m = gtid / (DIN * DOUT);
    int r = gtid - m * (DIN * DOUT);
    int k = r >> 6, o = r & 63;
    wth[(m * DOUT + o) * DIN + k] = (f16)w[gtid];
  }
}

// ---------------------------------------------------------------------------
// Projection, grid (1024, 3): one wave per block, one m per block (unchanged
// to isolate the attn change).
// ---------------------------------------------------------------------------
__global__ __launch_bounds__(64) void proj_kernel(
    const float* __restrict__ x, const f16* __restrict__ wth,
    f16* __restrict__ qh, f16* __restrict__ kh, f16* __restrict__ vth) {
  __shared__ alignas(16) f16 tbuf[64 * 24];
  const int lane = threadIdx.x;
  const int c = lane & 15, g = lane >> 4;
  const int m = blockIdx.y;
  const int tb = blockIdx.x * 16;
  const int b = tb >> 12, s0 = tb & 4095;

  f16x8 a[8];
  {
    const float* xr = x + (size_t)(tb + c) * DIN + g * 8;
#pragma unroll
    for (int ks = 0; ks < 8; ++ks) {
      f32x4 lo = *(const f32x4*)(xr + ks * 32);
      f32x4 hi = *(const f32x4*)(xr + ks * 32 + 4);
      f16x8 av;
#pragma unroll
      for (int j = 0; j < 4; ++j) { av[j] = (f16)lo[j]; av[j + 4] = (f16)hi[j]; }
      a[ks] = av;
    }
  }

  const f16* wb = wth + (size_t)m * DOUT * DIN + (size_t)c * DIN + g * 8;
  f32x4 acc[4];
#pragma unroll
  for (int nt = 0; nt < 4; ++nt) acc[nt] = (f32x4){0.f, 0.f, 0.f, 0.f};
#pragma unroll
  for (int ks = 0; ks < 8; ++ks)
#pragma unroll
    for (int nt = 0; nt < 4; ++nt) {
      f16x8 bf = *(const f16x8*)(wb + (size_t)(nt * 16) * DIN + ks * 32);
      acc[nt] = __builtin_amdgcn_mfma_f32_16x16x32_f16(a[ks], bf, acc[nt], 0, 0, 0);
    }

  if (m < 2) {
#pragma unroll
    for (int nt = 0; nt < 4; ++nt)
#pragma unroll
      for (int rr = 0; rr < 4; ++rr)
        tbuf[(4 * g + rr) * 72 + nt * 16 + c] =
            (f16)(m == 0 ? acc[nt][rr] * QSCALE : acc[nt][rr]);
    const int rw = lane >> 2, cb = (lane & 3) * 16;
    f16x8 r0 = *(const f16x8*)&tbuf[rw * 72 + cb];
    f16x8 r1 = *(const f16x8*)&tbuf[rw * 72 + cb + 8];
    f16* dst = (m == 0 ? qh : kh) + (size_t)(tb + rw) * DOUT + cb;
    *(f16x8*)(dst) = r0;
    *(f16x8*)(dst + 8) = r1;
  } else {
#pragma unroll
    for (int nt = 0; nt < 4; ++nt)
#pragma unroll
      for (int rr = 0; rr < 4; ++rr)
        tbuf[(nt * 16 + c) * 24 + 4 * g + rr] = (f16)acc[nt][rr];
    f16x8 r0 = *(const f16x8*)&tbuf[lane * 24];
    f16x8 r1 = *(const f16x8*)&tbuf[lane * 24 + 8];
    f16* dst = vth + ((size_t)b * DOUT + lane) * SLEN + s0;
    *(f16x8*)(dst) = r0;
    *(f16x8*)(dst + 8) = r1;
  }
}

// ---------------------------------------------------------------------------
// Flash attention v4: 512 blocks (4 b x 4 split x 32 q-blocks), 8 waves,
// each wave 16 q-rows.  16 waves/CU (2 blocks/CU, LDS 48 KB).  K/V staged
// once per block, shared by 8 waves.  NON-ATOMIC pO/pL partial outputs
// (R12's device-atomic merge cost ~72 MB of coherent traffic).  Combine
// kernel sums splits and divides (PSHIFT2 cancels).
// ---------------------------------------------------------------------------
__global__ __launch_bounds__(512, 4) void attn_kernel(
    const f16* __restrict__ qh, const f16* __restrict__ kh,
    const f16* __restrict__ vth, float* __restrict__ pO,
    float* __restrict__ pL) {
  __shared__ alignas(16) f16 kb[2][KVBLK * 64];   // 16 KB
  __shared__ alignas(16) f16 vb[2][KVBLK * 64];   // 16 KB
  __shared__ alignas(16) f16 pbuf[8][16 * 64];    // 16 KB

  const int tid = threadIdx.x;
  const int lane = tid & 63;
  const int c = lane & 15, g = lane >> 4;
  const int wv = tid >> 6;

  // bijective XCD-contiguous swizzle (nwg=512 = 8 x 64)
  const int wg = ((blockIdx.x & 7) << 6) + (blockIdx.x >> 3);
  const int b = wg >> 7;
  const int split = (wg >> 5) & 3;                // 0..3
  const int qb = wg & 31;                         // 0..31
  const int q0 = qb * QBLK + wv * 16;             // this wave's 16 rows
  const int kv0 = split * CHUNK;

  f16* plds = pbuf[wv];

  // staging map: 512 threads x 16B cover one 64x64 f16 tile (8 KB)
  const int srow = tid >> 3;                      // 0..63
  const int scol = (tid & 7) * 8;
  const f16* kgbase = kh + (size_t)b * SLEN * DOUT;
  const f16* vgbase = vth + (size_t)b * DOUT * SLEN;

  // Q frags (pre-scaled by 0.125*log2e)
  f16x8 qf[2];
  {
    const f16* qr = qh + ((size_t)(b * SLEN + q0 + c)) * DOUT + g * 8;
    qf[0] = *(const f16x8*)(qr);
    qf[1] = *(const f16x8*)(qr + 32);
  }

  f32x4 oacc[4];
#pragma unroll
  for (int nt = 0; nt < 4; ++nt) oacc[nt] = (f32x4){0.f, 0.f, 0.f, 0.f};
  float lrun = 0.f;
  const f32x4 zinit = (f32x4){-PSHIFT2, -PSHIFT2, -PSHIFT2, -PSHIFT2};

  auto stage = [&](int sel, int kv) {
    int sw = scol ^ ((srow & 7) << 3);            // source-side swizzle
    GLD16(kgbase + (size_t)(kv + srow) * DOUT + sw,
          (char*)(&kb[sel][0]) + wv * 1024);
    GLD16(vgbase + (size_t)srow * SLEN + kv + sw,
          (char*)(&vb[sel][0]) + wv * 1024);
  };

  stage(0, kv0);
  __syncthreads();

#pragma unroll 2
  for (int t = 0; t < NT; ++t) {
    const int sel = t & 1;
    if (t + 1 < NT) stage(sel ^ 1, kv0 + (t + 1) * KVBLK);

    // ---- S^T = K x Q^T; C-init = -PSHIFT2 (shift folded into MFMA) ----
    f32x4 sacc[4];
    __builtin_amdgcn_s_setprio(1);
#pragma unroll
    for (int t4 = 0; t4 < 4; ++t4) {
      f16x8 k0 = *(const f16x8*)&kb[sel][(16 * t4 + c) * 64 + 8 * (g ^ (c & 7))];
      f16x8 k1 = *(const f16x8*)&kb[sel][(16 * t4 + c) * 64 + 8 * ((g + 4) ^ (c & 7))];
      sacc[t4] = __builtin_amdgcn_mfma_f32_16x16x32_f16(k0, qf[0], zinit, 0, 0, 0);
      sacc[t4] = __builtin_amdgcn_mfma_f32_16x16x32_f16(k1, qf[1], sacc[t4], 0, 0, 0);
    }
    __builtin_amdgcn_s_setprio(0);

    // ---- lane-local exp2; pack via cvt_pkrtz ----
    f16x4 pk[4];
#pragma unroll
    for (int t4 = 0; t4 < 4; ++t4) {
      float e0 = exp2f(sacc[t4][0]), e1 = exp2f(sacc[t4][1]);
      float e2 = exp2f(sacc[t4][2]), e3 = exp2f(sacc[t4][3]);
      lrun += (e0 + e1) + (e2 + e3);
      f16x2 a0 = pkrtz(e0, e1), a1 = pkrtz(e2, e3);
      pk[t4] = (f16x4){a0[0], a0[1], a1[0], a1[1]};
    }

    // ---- P^T -> wave-private LDS ----
#pragma unroll
    for (int t4 = 0; t4 < 4; ++t4)
      *(f16x4*)&plds[c * 64 + ((16 * t4 + 4 * g) ^ ((c & 7) << 3))] = pk[t4];

    // ---- PV ----
    __builtin_amdgcn_s_setprio(1);
#pragma unroll
    for (int s2 = 0; s2 < 2; ++s2) {
      f16x8 pa = *(const f16x8*)&plds[c * 64 + ((s2 * 32 + g * 8) ^ ((c & 7) << 3))];
#pragma unroll
      for (int nt = 0; nt < 4; ++nt) {
        f16x8 vf = *(const f16x8*)&vb[sel][(16 * nt + c) * 64 + 8 * ((g + 4 * s2) ^ (c & 7))];
        oacc[nt] = __builtin_amdgcn_mfma_f32_16x16x32_f16(pa, vf, oacc[nt], 0, 0, 0);
      }
    }
    __builtin_amdgcn_s_setprio(0);

    __syncthreads();  // drains staging vmcnt; guards buffer reuse
  }

  // ---- write partials (non-atomic streaming stores) ----
  const size_t rowb = (size_t)b * SLEN + q0;
  float* po = pO + ((size_t)split * (NB * SLEN) + rowb) * DOUT;
#pragma unroll
  for (int nt = 0; nt < 4; ++nt)
#pragma unroll
    for (int r = 0; r < 4; ++r)
      po[(size_t)(4 * g + r) * DOUT + nt * 16 + c] = oacc[nt][r];
  lrun += __shfl_xor(lrun, 16);
  lrun += __shfl_xor(lrun, 32);
  if (lane < 16) pL[(size_t)split * (NB * SLEN) + rowb + lane] = lrun;
}

// ---------------------------------------------------------------------------
// Combine: out = (sum_s pO_s) / (sum_s pL_s)  (pure sums; PSHIFT2 cancels)
// ---------------------------------------------------------------------------
__global__ __launch_bounds__(256) void combine_kernel(
    const float* __restrict__ pO, const float* __restrict__ pL,
    float* __restrict__ out) {
  int i = blockIdx.x * 256 + threadIdx.x;   // 0 .. 262143 (f32x4 groups)
  int row = i >> 4;
  int c4 = (i & 15) * 4;
  f32x4 a = (f32x4){0.f, 0.f, 0.f, 0.f};
  float L = 0.f;
#pragma unroll
  for (int s = 0; s < KVSPLIT; ++s) {
    a += *(const f32x4*)&pO[((size_t)s * (NB * SLEN) + row) * DOUT + c4];
    L += pL[(size_t)s * (NB * SLEN) + row];
  }
  float rl = 1.0f / L;
  *(f32x4*)&out[(size_t)row * DOUT + c4] = a * rl;
}

extern "C" void kernel_launch(void* const* d_in, const int* in_sizes, int n_in,
                              void* d_out, int out_size, void* d_ws, size_t ws_size,
                              hipStream_t stream) {
  const float* x = (const float*)d_in[0];   // [4,4096,256] f32
  const float* w = (const float*)d_in[1];   // [3,256,64]   f32
  float* out = (float*)d_out;               // [4,4096,64]  f32

  const size_t NE = (size_t)NB * SLEN * DOUT;  // 1,048,576
  f16* qh = (f16*)d_ws;                        // 2 MB
  f16* kh = qh + NE;                           // 2 MB
  f16* vth = kh + NE;                          // 2 MB [b][d][s]
  f16* wth = vth + NE;                         // 96 KB
  float* pO = (float*)(wth + 3 * DIN * DOUT);  // 16 MB [split][row][64]
  float* pL = pO + (size_t)KVSPLIT * NE;       // 256 KB [split][row]

  hipLaunchKernelGGL(setup_kernel, dim3(192), dim3(256), 0, stream, w, wth);
  hipLaunchKernelGGL(proj_kernel, dim3(NB * SLEN / 16, 3), dim3(64), 0, stream,
                     x, wth, qh, kh, vth);
  hipLaunchKernelGGL(attn_kernel, dim3(NB * KVSPLIT * (SLEN / QBLK)), dim3(512),
                     0, stream, qh, kh, vth, pO, pL);
  hipLaunchKernelGGL(combine_kernel, dim3(NB * SLEN * DOUT / 4 / 256), dim3(256),
                     0, stream, pO, pL, out);
}